// Round 10
// baseline (59.498 us; speedup 1.0000x reference)
//
#include <hip/hip_runtime.h>
#include <math.h>

static constexpr int   B    = 256;   // batch
static constexpr int   D    = 256;   // feature dim
static constexpr int   NSV  = 512;   // P == Q
static constexpr int   NB   = 2;     // batches per block
static constexpr int   NBLK = B / NB;     // 128 blocks
static constexpr int   NT   = 64;         // ONE wave -> no barriers at all
static constexpr int   PR   = 64;         // panel rows (thread = row)
static constexpr int   NPAN = 2 * NSV / PR;  // 16 panels (0..7 sv1, 8..15 sv0)
static constexpr int   KC   = 64;         // chunk floats per row
static constexpr int   SPR  = KC / 4;     // 16 f4 slots per row
static constexpr int   NCH  = D / KC;     // 4 chunks
static constexpr int   NS   = NPAN * NCH; // 64 stages
static constexpr float G    = 0.1f;
static constexpr float CSH  = 26.0f;      // fixed LSE shift; cancels in LSE0-LSE1

typedef float f32x2 __attribute__((ext_vector_type(2)));

__device__ __forceinline__ void gld16(const void* g, void* l) {
    __builtin_amdgcn_global_load_lds((__attribute__((address_space(1))) void*)g,
                                     (__attribute__((address_space(3))) void*)l,
                                     16, 0, 0);
}

__global__ __launch_bounds__(NT)
void k_one(const float* __restrict__ x,
           const float* __restrict__ sv1,
           const float* __restrict__ sv0,
           const float* __restrict__ a1,
           const float* __restrict__ a0,
           float* __restrict__ out)
{
    __shared__ float tile[2][PR * KC];   // 2 x 16 KiB SV chunk buffers
    __shared__ float alds[2 * NSV];      // 4 KiB alphas (a1 then a0)

    const int t     = threadIdx.x;       // lane == local panel row
    const int bbase = blockIdx.x * NB;
    const float* __restrict__ xw = x + (size_t)bbase * D;  // block-uniform

    // ---- stage all alphas once (4 gld16/lane; drained by first vmcnt wait) ----
    #pragma unroll
    for (int i = 0; i < (2 * NSV / 4) / NT; ++i) {   // 4
        const int f = i * NT + t;                    // f4 slot 0..255
        const float* asrc = (f < NSV / 4) ? (a1 + f * 4) : (a0 + (f - NSV / 4) * 4);
        gld16(asrc, &alds[f * 4]);
    }

    // SV panel-chunk staging: linear LDS dest, XOR-swizzled global source
    auto stage = [&](int s) {
        const int pn = s >> 2, c = s & 3;
        float* buf = tile[s & 1];
        const float* base = (pn < NPAN / 2
                                 ? sv1 + (size_t)pn * PR * D
                                 : sv0 + (size_t)(pn - NPAN / 2) * PR * D) + c * KC;
        #pragma unroll
        for (int i = 0; i < (PR * SPR) / NT; ++i) {  // 16 slots/lane
            const int f  = i * NT + t;
            const int rr = f >> 4;          // local row 0..63
            const int p  = f & 15;          // physical f4 slot
            const int q  = p ^ (rr & 7);    // logical slot (involution)
            gld16(base + (size_t)rr * D + q * 4, buf + f * 4);
        }
    };

    auto compute = [&](int s, f32x2& ssq, f32x2& d0, f32x2& d1) {
        const int c = s & 3;
        const float4* tf = reinterpret_cast<const float4*>(tile[s & 1]);
        const float*  xc = xw + c * KC;
        #pragma unroll 4
        for (int kk = 0; kk < SPR; ++kk) {
            const int p = kk ^ (t & 7);                 // de-swizzle
            const float4 s4 = tf[(t << 4) + p];
            const f32x2 sa = {s4.x, s4.y};
            const f32x2 sb = {s4.z, s4.w};
            const float4 x0 = *reinterpret_cast<const float4*>(xc + 0 * D + kk * 4);
            const float4 x1 = *reinterpret_cast<const float4*>(xc + 1 * D + kk * 4);
            ssq = __builtin_elementwise_fma(sa, sa, ssq);
            ssq = __builtin_elementwise_fma(sb, sb, ssq);
            d0 = __builtin_elementwise_fma(sa, (f32x2){x0.x, x0.y}, d0);
            d0 = __builtin_elementwise_fma(sb, (f32x2){x0.z, x0.w}, d0);
            d1 = __builtin_elementwise_fma(sa, (f32x2){x1.x, x1.y}, d1);
            d1 = __builtin_elementwise_fma(sb, (f32x2){x1.z, x1.w}, d1);
        }
        // tile reads consumed before the next gld16 overwrites this buffer
        asm volatile("s_waitcnt lgkmcnt(0)" ::: "memory");
        __builtin_amdgcn_sched_barrier(0);
    };

    // ---- barrier-free 64-stage pipeline, depth-2 prefetch, counted vmcnt ----
    stage(0);
    stage(1);

    float es1_0 = 0.f, es1_1 = 0.f, es0_0 = 0.f, es0_1 = 0.f;

    for (int pn = 0; pn < NPAN; ++pn) {
        f32x2 ssq = {0.f, 0.f}, d0 = {0.f, 0.f}, d1 = {0.f, 0.f};
        #pragma unroll
        for (int c = 0; c < NCH; ++c) {
            const int s = pn * NCH + c;
            if (s < NS - 1) asm volatile("s_waitcnt vmcnt(16)" ::: "memory");
            else            asm volatile("s_waitcnt vmcnt(0)"  ::: "memory");
            __builtin_amdgcn_sched_barrier(0);
            compute(s, ssq, d0, d1);
            if (s + 2 < NS) stage(s + 2);
        }
        // ---- panel fold: score -> exp -> running sums ----
        const float av  = alds[pn * PR + t];    // LDS read, conflict-free
        const float lal = __logf(av);
        const float sq  = ssq.x + ssq.y;
        const float e0  = __expf(G * (sq - 2.f * (d0.x + d0.y)) - lal - CSH);
        const float e1  = __expf(G * (sq - 2.f * (d1.x + d1.y)) - lal - CSH);
        if (pn < NPAN / 2) { es1_0 += e0; es1_1 += e1; }
        else               { es0_0 += e0; es0_1 += e1; }
    }

    // ---- full-wave reduce (4 sums) and direct output write ----
    #pragma unroll
    for (int off = 32; off > 0; off >>= 1) {
        es1_0 += __shfl_xor(es1_0, off);
        es1_1 += __shfl_xor(es1_1, off);
        es0_0 += __shfl_xor(es0_0, off);
        es0_1 += __shfl_xor(es0_1, off);
    }
    if (t == 0) {
        out[bbase + 0] = __logf(es0_0) - __logf(es1_0);   // CSH cancels
        out[bbase + 1] = __logf(es0_1) - __logf(es1_1);
    }
}

extern "C" void kernel_launch(void* const* d_in, const int* in_sizes, int n_in,
                              void* d_out, int out_size, void* d_ws, size_t ws_size,
                              hipStream_t stream) {
    const float* x   = (const float*)d_in[0];
    const float* sv1 = (const float*)d_in[1];
    const float* sv0 = (const float*)d_in[2];
    const float* a1  = (const float*)d_in[3];
    const float* a0  = (const float*)d_in[4];
    float* out = (float*)d_out;

    k_one<<<NBLK, NT, 0, stream>>>(x, sv1, sv0, a1, a0, out);
}

// Round 11
// 16.059 us; speedup vs baseline: 3.7050x; 3.7050x over previous
//
#include <hip/hip_runtime.h>
#include <math.h>

static constexpr int   B   = 256;   // batch
static constexpr int   D   = 256;   // feature dim
static constexpr int   NSV = 512;   // P == Q
static constexpr int   NT  = 512;   // 8 waves per block, 1 block/CU
static constexpr int   RW  = 128;   // rows per wave (2 groups of 64)
static constexpr float G   = 0.1f;
static constexpr float CSH = 26.0f; // fixed LSE shift; cancels in LSE0-LSE1

__global__ __launch_bounds__(NT)
void k_one(const float* __restrict__ x,
           const float* __restrict__ sv1,
           const float* __restrict__ sv0,
           const float* __restrict__ a1,
           const float* __restrict__ a0,
           float* __restrict__ out)
{
    __shared__ float sred[8];

    const int t = threadIdx.x;
    const int l = t & 63;
    const int w = t >> 6;
    const int b = blockIdx.x;

    // 2*x[b][4l..4l+3] — one coalesced float4 per lane, reused for all rows
    const float4 xv = *reinterpret_cast<const float4*>(x + (size_t)b * D + 4 * l);
    const float4 px = {2.f * xv.x, 2.f * xv.y, 2.f * xv.z, 2.f * xv.w};

    const int set = w >> 2;                  // waves 0-3: sv1, 4-7: sv0
    const float* __restrict__ svb = set ? sv0 : sv1;
    const float* __restrict__ ab  = set ? a0  : a1;
    const int rbase = (w & 3) * RW;

    float es = 0.f;

    #pragma unroll
    for (int g = 0; g < 2; ++g) {
        const int gbase = rbase + g * 64;
        const float* __restrict__ src = svb + (size_t)gbase * D + 4 * l;

        // per-lane partials for 64 rows; rows pipelined in blocks of 8,
        // depth-2 register prefetch (all indices compile-time -> registers)
        float  q[64];
        float4 bufs[3][8];

        #pragma unroll
        for (int j = 0; j < 8; ++j)
            bufs[0][j] = *reinterpret_cast<const float4*>(src + (size_t)j * D);
        #pragma unroll
        for (int j = 0; j < 8; ++j)
            bufs[1][j] = *reinterpret_cast<const float4*>(src + (size_t)(8 + j) * D);

        #pragma unroll
        for (int blk = 0; blk < 8; ++blk) {
            if (blk + 2 < 8) {
                #pragma unroll
                for (int j = 0; j < 8; ++j)
                    bufs[(blk + 2) % 3][j] =
                        *reinterpret_cast<const float4*>(src + (size_t)((blk + 2) * 8 + j) * D);
            }
            #pragma unroll
            for (int j = 0; j < 8; ++j) {
                const float4 s = bufs[blk % 3][j];
                float acc = s.x * (s.x - px.x);
                acc = fmaf(s.y, s.y - px.y, acc);
                acc = fmaf(s.z, s.z - px.z, acc);
                acc = fmaf(s.w, s.w - px.w, acc);
                q[blk * 8 + j] = acc;
            }
            // fence: keep future-block loads from hoisting (bounds VGPR pressure)
            __builtin_amdgcn_sched_barrier(0);
        }

        // butterfly transpose-reduce: 6 stages, 63 shfl -> lane l holds full
        // sum for row gbase + l
        #pragma unroll
        for (int st = 0; st < 6; ++st) {
            const int m = 1 << st;
            #pragma unroll
            for (int k = 0; k < (64 >> (st + 1)); ++k) {
                const float lo = q[2 * k], hi = q[2 * k + 1];
                const bool  up = (l & m) != 0;
                const float mine   = up ? hi : lo;
                const float theirs = up ? lo : hi;
                q[k] = mine + __shfl_xor(theirs, m);
            }
        }

        const float alpha = ab[gbase + l];     // coalesced
        es += __expf(G * q[0] - __logf(alpha) - CSH);
    }

    // wave total, then 8-wave combine in LDS
    #pragma unroll
    for (int off = 32; off > 0; off >>= 1) es += __shfl_xor(es, off);
    if (l == 0) sred[w] = es;
    __syncthreads();
    if (t == 0) {
        const float S1 = sred[0] + sred[1] + sred[2] + sred[3];
        const float S0 = sred[4] + sred[5] + sred[6] + sred[7];
        out[b] = __logf(S0) - __logf(S1);      // CSH cancels
    }
}

extern "C" void kernel_launch(void* const* d_in, const int* in_sizes, int n_in,
                              void* d_out, int out_size, void* d_ws, size_t ws_size,
                              hipStream_t stream) {
    const float* x   = (const float*)d_in[0];
    const float* sv1 = (const float*)d_in[1];
    const float* sv0 = (const float*)d_in[2];
    const float* a1  = (const float*)d_in[3];
    const float* a0  = (const float*)d_in[4];
    float* out = (float*)d_out;

    k_one<<<B, NT, 0, stream>>>(x, sv1, sv0, a1, a0, out);
}

// Round 12
// 14.720 us; speedup vs baseline: 4.0419x; 1.0909x over previous
//
#include <hip/hip_runtime.h>
#include <math.h>

static constexpr int   B    = 256;   // batch
static constexpr int   D    = 256;   // feature dim
static constexpr int   NSV  = 512;   // P == Q
static constexpr int   RG   = 16;    // SV row-group slices
static constexpr int   RPS  = NSV / RG;   // 32 rows per set per block
static constexpr int   RPB  = 2 * RPS;    // 64 tile rows (set1 then set0)
static constexpr int   NB   = 4;          // batches per block
static constexpr int   NT   = 64;         // ONE wave per block -> no barriers
static constexpr int   KC   = 64;         // chunk floats per row
static constexpr int   SPR  = KC / 4;     // 16 f4 slots per row
static constexpr int   RGB  = RG * B;     // 4096 slots per set
static constexpr float G    = 0.1f;
static constexpr float CSH  = 26.0f;      // fixed LSE shift; cancels in LSE0-LSE1

typedef float f32x2 __attribute__((ext_vector_type(2)));

__device__ __forceinline__ void gld16(const void* g, void* l) {
    __builtin_amdgcn_global_load_lds((__attribute__((address_space(1))) void*)g,
                                     (__attribute__((address_space(3))) void*)l,
                                     16, 0, 0);
}

// Data-as-flag slot protocol: partial p>0 encoded as enc=-2-p (< -2).
// Unwritten states (0xAA poison=-3e-13, zeros, positive leftovers) are >= -1.5.
__device__ __forceinline__ void st_slot(float* p, float v) {
    __hip_atomic_store(p, -2.0f - v, __ATOMIC_RELAXED, __HIP_MEMORY_SCOPE_AGENT);
}
__device__ __forceinline__ float ld_slot(const float* p) {
    float e;
    do { e = __hip_atomic_load(p, __ATOMIC_RELAXED, __HIP_MEMORY_SCOPE_AGENT); }
    while (!(e < -1.5f));
    return -2.0f - e;
}

__global__ __launch_bounds__(NT)
void k_all(const float* __restrict__ x,
           const float* __restrict__ sv1,
           const float* __restrict__ sv0,
           const float* __restrict__ a1,
           const float* __restrict__ a0,
           float* __restrict__ ws,
           float* __restrict__ out)
{
    __shared__ float tile[2][RPB * KC];   // 2 x 16 KiB SV chunk buffers
    __shared__ float xls[NB * D];         // 4 KiB x rows (read as broadcasts)

    const int t     = threadIdx.x;        // == lane; == tile row
    const int rg    = blockIdx.x;
    const int bbase = blockIdx.y * NB;

    // ---- stage x rows once (linear, vmcnt slots 0..3) ----
    {
        const float* xsrc = x + (size_t)bbase * D;
        #pragma unroll
        for (int i = 0; i < (NB * D / 4) / NT; ++i) {   // 4 slots/lane
            const int f = i * NT + t;
            gld16(xsrc + f * 4, &xls[f * 4]);
        }
    }

    // SV chunk staging: linear LDS dest, XOR-swizzled global source (involution)
    auto stage = [&](int c, int buf) {
        #pragma unroll
        for (int i = 0; i < (RPB * SPR) / NT; ++i) {   // 16 slots/lane
            const int f  = i * NT + t;
            const int rr = f >> 4;          // tile row 0..63
            const int p  = f & 15;          // physical f4 slot
            const int q  = p ^ (rr & 7);    // logical slot
            const float* src = (rr < RPS)
                ? (sv1 + (size_t)(rg * RPS + rr) * D)
                : (sv0 + (size_t)(rg * RPS + (rr - RPS)) * D);
            gld16(src + c * KC + q * 4, &tile[buf][f * 4]);
        }
    };

    f32x2 ssq = {0.f, 0.f};
    f32x2 d0 = {0.f, 0.f}, d1 = {0.f, 0.f}, d2 = {0.f, 0.f}, d3 = {0.f, 0.f};

    auto compute = [&](int cc, int buf) {
        const float4* tf = reinterpret_cast<const float4*>(&tile[buf][0]);
        const float4* xf = reinterpret_cast<const float4*>(xls) + cc * SPR;
        #pragma unroll 4
        for (int kk = 0; kk < SPR; ++kk) {
            const int p = kk ^ (t & 7);                 // de-swizzle
            const float4 s4 = tf[(t << 4) + p];
            const f32x2 sa = {s4.x, s4.y};
            const f32x2 sb = {s4.z, s4.w};
            const float4 x0 = xf[0 * (D / 4) + kk];     // broadcast ds_read_b128
            const float4 x1 = xf[1 * (D / 4) + kk];
            const float4 x2 = xf[2 * (D / 4) + kk];
            const float4 x3 = xf[3 * (D / 4) + kk];
            ssq = __builtin_elementwise_fma(sa, sa, ssq);
            ssq = __builtin_elementwise_fma(sb, sb, ssq);
            d0 = __builtin_elementwise_fma(sa, (f32x2){x0.x, x0.y}, d0);
            d0 = __builtin_elementwise_fma(sb, (f32x2){x0.z, x0.w}, d0);
            d1 = __builtin_elementwise_fma(sa, (f32x2){x1.x, x1.y}, d1);
            d1 = __builtin_elementwise_fma(sb, (f32x2){x1.z, x1.w}, d1);
            d2 = __builtin_elementwise_fma(sa, (f32x2){x2.x, x2.y}, d2);
            d2 = __builtin_elementwise_fma(sb, (f32x2){x2.z, x2.w}, d2);
            d3 = __builtin_elementwise_fma(sa, (f32x2){x3.x, x3.y}, d3);
            d3 = __builtin_elementwise_fma(sb, (f32x2){x3.z, x3.w}, d3);
        }
        // all ds_reads of this buffer consumed before next gld16 targets it
        asm volatile("s_waitcnt lgkmcnt(0)" ::: "memory");
        __builtin_amdgcn_sched_barrier(0);
    };

    // barrier-free counted-vmcnt pipeline (single wave owns the whole block)
    stage(0, 0);
    stage(1, 1);

    asm volatile("s_waitcnt vmcnt(16)" ::: "memory");  // x + c0 done
    __builtin_amdgcn_sched_barrier(0);
    compute(0, 0);
    stage(2, 0);

    asm volatile("s_waitcnt vmcnt(16)" ::: "memory");  // c1 done
    __builtin_amdgcn_sched_barrier(0);
    compute(1, 1);
    stage(3, 1);

    asm volatile("s_waitcnt vmcnt(16)" ::: "memory");  // c2 done
    __builtin_amdgcn_sched_barrier(0);
    compute(2, 0);

    asm volatile("s_waitcnt vmcnt(0)" ::: "memory");   // c3 done
    __builtin_amdgcn_sched_barrier(0);
    compute(3, 1);

    // ---- epilogue: score -> exp -> 32-lane reduce per set ----
    const int   rloc = t & (RPS - 1);
    const int   set  = t >> 5;            // 0 = sv1 rows, 1 = sv0 rows
    const float av   = set ? a0[rg * RPS + rloc] : a1[rg * RPS + rloc];
    const float lal  = __logf(av);
    const float sq   = ssq.x + ssq.y;

    float e0 = __expf(G * (sq - 2.f * (d0.x + d0.y)) - lal - CSH);
    float e1 = __expf(G * (sq - 2.f * (d1.x + d1.y)) - lal - CSH);
    float e2 = __expf(G * (sq - 2.f * (d2.x + d2.y)) - lal - CSH);
    float e3 = __expf(G * (sq - 2.f * (d3.x + d3.y)) - lal - CSH);

    #pragma unroll
    for (int off = 16; off > 0; off >>= 1) {   // reduce within 32-lane halves
        e0 += __shfl_xor(e0, off);
        e1 += __shfl_xor(e1, off);
        e2 += __shfl_xor(e2, off);
        e3 += __shfl_xor(e3, off);
    }
    if (t == 0 || t == 32) {                   // publish 4 slots per set
        float* dst = ws + (size_t)set * RGB + rg * B + bbase;
        st_slot(&dst[0], e0);
        st_slot(&dst[1], e1);
        st_slot(&dst[2], e2);
        st_slot(&dst[3], e3);
    }

    // ---- rg==0 blocks finalize their 4 outputs (spin on 128 column slots) ----
    if (rg == 0) {
        const int rgf = t >> 2;               // 0..15
        const int bo  = t & 3;
        const int b   = bbase + bo;
        float S1 = ld_slot(&ws[0 * RGB + rgf * B + b]);   // sv1 partials
        float S0 = ld_slot(&ws[1 * RGB + rgf * B + b]);   // sv0 partials
        #pragma unroll
        for (int off = 4; off <= 32; off <<= 1) {         // sum over rg bits
            S1 += __shfl_xor(S1, off);
            S0 += __shfl_xor(S0, off);
        }
        if (t < NB) out[bbase + t] = __logf(S0) - __logf(S1);  // CSH cancels
    }
}

extern "C" void kernel_launch(void* const* d_in, const int* in_sizes, int n_in,
                              void* d_out, int out_size, void* d_ws, size_t ws_size,
                              hipStream_t stream) {
    const float* x   = (const float*)d_in[0];
    const float* sv1 = (const float*)d_in[1];
    const float* sv0 = (const float*)d_in[2];
    const float* a1  = (const float*)d_in[3];
    const float* a0  = (const float*)d_in[4];
    float* ws  = (float*)d_ws;
    float* out = (float*)d_out;

    dim3 g1(RG, B / NB);   // 16 x 64 = 1024 single-wave blocks (4/CU, all resident)
    k_all<<<g1, NT, 0, stream>>>(x, sv1, sv0, a1, a0, ws, out);
}

// Round 13
// 13.750 us; speedup vs baseline: 4.3271x; 1.0706x over previous
//
#include <hip/hip_runtime.h>
#include <math.h>

static constexpr int   B    = 256;   // batch
static constexpr int   D    = 256;   // feature dim
static constexpr int   NSV  = 512;   // P == Q
static constexpr int   RG   = 16;    // SV row-group slices
static constexpr int   RPS  = NSV / RG;   // 32 rows per set per block
static constexpr int   RPB  = 2 * RPS;    // 64 tile rows (set1 then set0)
static constexpr int   NB   = 4;          // batches per block
static constexpr int   NT   = 64;         // ONE wave per block -> no barriers
static constexpr int   KC   = 64;         // chunk floats per row
static constexpr int   SPR  = KC / 4;     // 16 f4 slots per row
static constexpr float G    = 0.1f;
static constexpr float CSH  = 26.0f;      // fixed LSE shift; cancels in LSE0-LSE1

typedef float f32x2 __attribute__((ext_vector_type(2)));

__device__ __forceinline__ void gld16(const void* g, void* l) {
    __builtin_amdgcn_global_load_lds((__attribute__((address_space(1))) void*)g,
                                     (__attribute__((address_space(3))) void*)l,
                                     16, 0, 0);
}

__global__ __launch_bounds__(NT)
void k_all(const float* __restrict__ x,
           const float* __restrict__ sv1,
           const float* __restrict__ sv0,
           const float* __restrict__ a1,
           const float* __restrict__ a0,
           float* __restrict__ ws)   // transposed: ws[(set*B + b)*RG + rg]
{
    __shared__ float tile[2][RPB * KC];   // 2 x 16 KiB SV chunk buffers
    __shared__ float xls[NB * D];         // 4 KiB x rows (read as broadcasts)

    const int t     = threadIdx.x;        // == lane; == tile row
    const int rg    = blockIdx.x;
    const int bbase = blockIdx.y * NB;

    // ---- stage x rows once (linear, vmcnt slots 0..3) ----
    {
        const float* xsrc = x + (size_t)bbase * D;
        #pragma unroll
        for (int i = 0; i < (NB * D / 4) / NT; ++i) {   // 4 slots/lane
            const int f = i * NT + t;
            gld16(xsrc + f * 4, &xls[f * 4]);
        }
    }

    // SV chunk staging: linear LDS dest, XOR-swizzled global source (involution)
    auto stage = [&](int c, int buf) {
        #pragma unroll
        for (int i = 0; i < (RPB * SPR) / NT; ++i) {   // 16 slots/lane
            const int f  = i * NT + t;
            const int rr = f >> 4;          // tile row 0..63
            const int p  = f & 15;          // physical f4 slot
            const int q  = p ^ (rr & 7);    // logical slot
            const float* src = (rr < RPS)
                ? (sv1 + (size_t)(rg * RPS + rr) * D)
                : (sv0 + (size_t)(rg * RPS + (rr - RPS)) * D);
            gld16(src + c * KC + q * 4, &tile[buf][f * 4]);
        }
    };

    f32x2 ssq = {0.f, 0.f};
    f32x2 d0 = {0.f, 0.f}, d1 = {0.f, 0.f}, d2 = {0.f, 0.f}, d3 = {0.f, 0.f};

    auto compute = [&](int cc, int buf) {
        const float4* tf = reinterpret_cast<const float4*>(&tile[buf][0]);
        const float4* xf = reinterpret_cast<const float4*>(xls) + cc * SPR;
        #pragma unroll 4
        for (int kk = 0; kk < SPR; ++kk) {
            const int p = kk ^ (t & 7);                 // de-swizzle
            const float4 s4 = tf[(t << 4) + p];
            const f32x2 sa = {s4.x, s4.y};
            const f32x2 sb = {s4.z, s4.w};
            const float4 x0 = xf[0 * (D / 4) + kk];     // broadcast ds_read_b128
            const float4 x1 = xf[1 * (D / 4) + kk];
            const float4 x2 = xf[2 * (D / 4) + kk];
            const float4 x3 = xf[3 * (D / 4) + kk];
            ssq = __builtin_elementwise_fma(sa, sa, ssq);
            ssq = __builtin_elementwise_fma(sb, sb, ssq);
            d0 = __builtin_elementwise_fma(sa, (f32x2){x0.x, x0.y}, d0);
            d0 = __builtin_elementwise_fma(sb, (f32x2){x0.z, x0.w}, d0);
            d1 = __builtin_elementwise_fma(sa, (f32x2){x1.x, x1.y}, d1);
            d1 = __builtin_elementwise_fma(sb, (f32x2){x1.z, x1.w}, d1);
            d2 = __builtin_elementwise_fma(sa, (f32x2){x2.x, x2.y}, d2);
            d2 = __builtin_elementwise_fma(sb, (f32x2){x2.z, x2.w}, d2);
            d3 = __builtin_elementwise_fma(sa, (f32x2){x3.x, x3.y}, d3);
            d3 = __builtin_elementwise_fma(sb, (f32x2){x3.z, x3.w}, d3);
        }
        // all ds_reads of this buffer consumed before next gld16 targets it
        asm volatile("s_waitcnt lgkmcnt(0)" ::: "memory");
        __builtin_amdgcn_sched_barrier(0);
    };

    // barrier-free counted-vmcnt pipeline (single wave owns the whole block)
    stage(0, 0);
    stage(1, 1);

    asm volatile("s_waitcnt vmcnt(16)" ::: "memory");  // x + c0 done
    __builtin_amdgcn_sched_barrier(0);
    compute(0, 0);
    stage(2, 0);

    asm volatile("s_waitcnt vmcnt(16)" ::: "memory");  // c1 done
    __builtin_amdgcn_sched_barrier(0);
    compute(1, 1);
    stage(3, 1);

    asm volatile("s_waitcnt vmcnt(16)" ::: "memory");  // c2 done
    __builtin_amdgcn_sched_barrier(0);
    compute(2, 0);

    asm volatile("s_waitcnt vmcnt(0)" ::: "memory");   // c3 done
    __builtin_amdgcn_sched_barrier(0);
    compute(3, 1);

    // ---- epilogue: score -> exp -> 32-lane reduce per set ----
    const int   rloc = t & (RPS - 1);
    const int   set  = t >> 5;            // 0 = sv1 rows, 1 = sv0 rows
    const float av   = set ? a0[rg * RPS + rloc] : a1[rg * RPS + rloc];
    const float lal  = __logf(av);
    const float sq   = ssq.x + ssq.y;

    float e0 = __expf(G * (sq - 2.f * (d0.x + d0.y)) - lal - CSH);
    float e1 = __expf(G * (sq - 2.f * (d1.x + d1.y)) - lal - CSH);
    float e2 = __expf(G * (sq - 2.f * (d2.x + d2.y)) - lal - CSH);
    float e3 = __expf(G * (sq - 2.f * (d3.x + d3.y)) - lal - CSH);

    #pragma unroll
    for (int off = 16; off > 0; off >>= 1) {   // reduce within 32-lane halves
        e0 += __shfl_xor(e0, off);
        e1 += __shfl_xor(e1, off);
        e2 += __shfl_xor(e2, off);
        e3 += __shfl_xor(e3, off);
    }
    if (t == 0 || t == 32) {
        // transposed publish: partials for one output are contiguous in rg
        float* dst = ws + ((size_t)set * B + bbase) * RG + rg;
        dst[0 * RG] = e0;
        dst[1 * RG] = e1;
        dst[2 * RG] = e2;
        dst[3 * RG] = e3;
    }
}

// out[b] = log(S0) - log(S1); CSH cancels. 4 blocks x 64 threads; each thread
// reads its output's 16+16 partials as 8 coalesced float4s.
__global__ __launch_bounds__(64)
void k_final(const float* __restrict__ ws, float* __restrict__ out)
{
    const int b = blockIdx.x * 64 + threadIdx.x;
    const float4* p1 = reinterpret_cast<const float4*>(ws + (size_t)b * RG);
    const float4* p0 = reinterpret_cast<const float4*>(ws + (size_t)(B + b) * RG);
    float4 s1 = p1[0], s0 = p0[0];
    #pragma unroll
    for (int i = 1; i < RG / 4; ++i) {
        const float4 a = p1[i], c = p0[i];
        s1.x += a.x; s1.y += a.y; s1.z += a.z; s1.w += a.w;
        s0.x += c.x; s0.y += c.y; s0.z += c.z; s0.w += c.w;
    }
    const float S1 = (s1.x + s1.y) + (s1.z + s1.w);
    const float S0 = (s0.x + s0.y) + (s0.z + s0.w);
    out[b] = __logf(S0) - __logf(S1);
}

extern "C" void kernel_launch(void* const* d_in, const int* in_sizes, int n_in,
                              void* d_out, int out_size, void* d_ws, size_t ws_size,
                              hipStream_t stream) {
    const float* x   = (const float*)d_in[0];
    const float* sv1 = (const float*)d_in[1];
    const float* sv0 = (const float*)d_in[2];
    const float* a1  = (const float*)d_in[3];
    const float* a0  = (const float*)d_in[4];
    float* ws  = (float*)d_ws;
    float* out = (float*)d_out;

    dim3 g1(RG, B / NB);   // 16 x 64 = 1024 single-wave blocks
    k_all<<<g1, NT, 0, stream>>>(x, sv1, sv0, a1, a0, ws);
    k_final<<<B / 64, 64, 0, stream>>>(ws, out);
}